// Round 4
// baseline (388.719 us; speedup 1.0000x reference)
//
#include <hip/hip_runtime.h>
#include <math.h>

#define NE  8
#define D   2048
#define TPB 256

__global__ __launch_bounds__(TPB) void router_main(
    const float* __restrict__ x, const float* __restrict__ Wg,
    float* __restrict__ outW, float* __restrict__ outI,
    float* __restrict__ ws, int N, int stride_rows)
{
  __shared__ float part[32];
  const int t    = threadIdx.x;
  const int lane = t & 63;
  const int wvid = t >> 6;

  float w[64];
  {
    const float4* wg4 = (const float4*)Wg + t * 16;
#pragma unroll
    for (int k = 0; k < 16; ++k) {
      float4 v = wg4[k];
      w[4*k+0] = v.x; w[4*k+1] = v.y; w[4*k+2] = v.z; w[4*k+3] = v.w;
    }
  }

  float impAcc = 0.f, cntAcc = 0.f;

  int row = blockIdx.x;
  float4 a = make_float4(0.f,0.f,0.f,0.f), b = a;
  if (row < N) {
    const float4* xr = (const float4*)(x + (size_t)row * D) + t * 2;
    a = xr[0]; b = xr[1];
  }

  for (; row < N; row += stride_rows) {
    int nrow = row + stride_rows;
    float4 na = make_float4(0.f,0.f,0.f,0.f), nb = na;
    if (nrow < N) {
      const float4* xr = (const float4*)(x + (size_t)nrow * D) + t * 2;
      na = xr[0]; nb = xr[1];
    }

    float xv[8] = {a.x,a.y,a.z,a.w,b.x,b.y,b.z,b.w};
    float acc[NE];
#pragma unroll
    for (int e = 0; e < NE; ++e) acc[e] = 0.f;
#pragma unroll
    for (int j = 0; j < 8; ++j)
#pragma unroll
      for (int e = 0; e < NE; ++e)
        acc[e] = fmaf(xv[j], w[j*8+e], acc[e]);

#pragma unroll
    for (int m = 1; m <= 4; m <<= 1)
#pragma unroll
      for (int e = 0; e < NE; ++e)
        acc[e] += __shfl_xor(acc[e], m, 64);
    const int eo = lane & 7;
    float v = acc[0];
#pragma unroll
    for (int e = 1; e < NE; ++e) v = (eo == e) ? acc[e] : v;
#pragma unroll
    for (int m = 8; m <= 32; m <<= 1) v += __shfl_xor(v, m, 64);

    if (lane < 8) part[wvid * 8 + lane] = v;
    __syncthreads();

    if (t < NE) {
      float h[NE];
#pragma unroll
      for (int e = 0; e < NE; ++e)
        h[e] = part[e] + part[8+e] + part[16+e] + part[24+e];

      int i1 = 0; float v1 = h[0];
#pragma unroll
      for (int e = 1; e < NE; ++e) if (h[e] > v1) { v1 = h[e]; i1 = e; }
      int i2 = -1; float v2 = -INFINITY;
#pragma unroll
      for (int e = 0; e < NE; ++e) if (e != i1 && h[e] > v2) { v2 = h[e]; i2 = e; }

      if (t == 0) {
        float e2 = expf(v2 - v1);
        float dd = 1.f / (1.f + e2);
        outW[(size_t)row*2]   = dd;
        outW[(size_t)row*2+1] = e2 * dd;
        outI[(size_t)row*2]   = (float)i1;
        outI[(size_t)row*2+1] = (float)i2;
      }

      float s = 0.f, pe = 0.f;
#pragma unroll
      for (int e = 0; e < NE; ++e) {
        float p = expf(h[e] - v1);
        s += p;
        if (e == t) pe = p;
      }
      impAcc += pe / s;
      cntAcc += (float)((t == i1) + (t == i2));
    }
    __syncthreads();
    a = na; b = nb;
  }

  if (t < NE) {
    atomicAdd(&ws[t],      impAcc);
    atomicAdd(&ws[NE + t], cntAcc);
  }
}

__global__ void router_final(const float* __restrict__ ws, float* __restrict__ out)
{
  if (threadIdx.x == 0 && blockIdx.x == 0) {
    float mi = 0.f, ml = 0.f;
    for (int e = 0; e < NE; ++e) { mi += ws[e]; ml += ws[NE + e]; }
    mi *= (1.f / NE); ml *= (1.f / NE);
    float vi = 0.f, vl = 0.f;
    for (int e = 0; e < NE; ++e) {
      float di = ws[e] - mi, dl = ws[NE + e] - ml;
      vi += di * di; vl += dl * dl;
    }
    float si = sqrtf(vi / (NE - 1));
    float sl = sqrtf(vl / (NE - 1));
    float cv = sl / (ml + 1e-6f) + si / (mi + 1e-6f);
    out[0] = cv * 0.01f;
  }
}

extern "C" void kernel_launch(void* const* d_in, const int* in_sizes, int n_in,
                              void* d_out, int out_size, void* d_ws, size_t ws_size,
                              hipStream_t stream) {
  const float* x  = (const float*)d_in[0];
  const float* Wg = (const float*)d_in[1];

  const int N = in_sizes[0] / D;
  float* out  = (float*)d_out;
  float* outW = out;
  float* outI = out + (size_t)N * 2;
  float* aux  = out + (size_t)N * 4;
  float* ws   = (float*)d_ws;

  hipMemsetAsync(d_ws, 0, 16 * sizeof(float), stream);

  int grid = 2048;
  if (grid > N) grid = N;
  router_main<<<grid, TPB, 0, stream>>>(x, Wg, outW, outI, ws, N, grid);
  router_final<<<1, 64, 0, stream>>>(ws, aux);
}